// Round 3
// baseline (374.009 us; speedup 1.0000x reference)
//
#include <hip/hip_runtime.h>
#include <hip/hip_bf16.h>

// Implicit-GEMM conv2d 3x3 VALID stride 1 via bf16 MFMA, fp32 accumulate.
// x: (32,64,112,112) f32  w: (128,64,3,3) f32  bias: (128)  out: (32,128,110,110) f32
// GEMM: M=Cout=128, K=(kh,kw,ci)=576, N=pixels. Block = one (n,oh) row,
// 128co x 128px tile, 4 waves. K-loop: double-buffered frags (prefetch kc+1
// during kc's 16 MFMAs), A from L2, B from LDS, zero barriers in the loop.

#define CIN   64
#define COUT  128
#define INH   112
#define INW   112
#define OUTH  110
#define OUTW  110
#define NB    32
#define KTOT  576           // k = (kh*3+kw)*64 + ci
#define NPIX  (NB*OUTH*OUTW)

typedef __attribute__((ext_vector_type(8))) short short8;     // 8 bf16 (4 VGPRs)
typedef __attribute__((ext_vector_type(4))) float f32x4;
typedef __attribute__((ext_vector_type(4))) unsigned int uint4v;

static __device__ __forceinline__ unsigned short f2bf(float f) {
    union { float f; unsigned int u; } v; v.f = f;
    return (unsigned short)((v.u + 0x7FFF + ((v.u >> 16) & 1)) >> 16);  // RNE
}
static __device__ __forceinline__ unsigned int pack2(float lo, float hi) {
    return (unsigned int)f2bf(lo) | ((unsigned int)f2bf(hi) << 16);
}

// ---------- pre-pass 1: x NCHW f32 -> NHWC bf16, direct global transpose ----------
// No LDS: item (w, grp) reads 8 ci (coalesced per-j across the 64 w-lanes),
// packs to short8, stores one dwordx4 (perfectly coalesced: 8 grp-lanes = 128 B run).
__global__ __launch_bounds__(256) void convert_x(const float* __restrict__ x,
                                                 unsigned short* __restrict__ xhwc) {
    const int h = blockIdx.x;                     // 0..111
    const int n = blockIdx.y;                     // 0..31
    const float* xp = x + ((size_t)n * CIN) * (INH * INW) + (size_t)h * INW;
    unsigned int* dst = (unsigned int*)(xhwc + ((size_t)(n * INH + h) * INW) * 64);
    for (int c = threadIdx.x; c < 896; c += 256) {       // 112 w x 8 ci-groups
        const int w = c >> 3, grp = c & 7;
        float v[8];
#pragma unroll
        for (int j = 0; j < 8; ++j)
            v[j] = xp[(size_t)(grp * 8 + j) * (INH * INW) + w];
        uint4v o = { pack2(v[0], v[1]), pack2(v[2], v[3]),
                     pack2(v[4], v[5]), pack2(v[6], v[7]) };
        *(uint4v*)&dst[(w * 64 + grp * 8) >> 1] = o;
    }
}

// ---------- pre-pass 2: weights -> bf16, fragment-major ----------
// A_packed halfword index: ((k>>3)*128 + m)*8 + (k&7), k=(kh*3+kw)*64+ci
__global__ __launch_bounds__(256) void prepack_w(const float* __restrict__ w,
                                                 unsigned short* __restrict__ ap) {
    int flat = blockIdx.x * 256 + threadIdx.x;    // 128*576 = 73728 exactly
    int m = flat / KTOT;
    int k = flat - m * KTOT;
    int khw = k >> 6, ci = k & 63;
    int kh = khw / 3, kw = khw - kh * 3;
    float v = w[((m * CIN + ci) * 3 + kh) * 3 + kw];
    ap[((k >> 3) * COUT + m) * 8 + (k & 7)] = f2bf(v);
}

// ---------- main GEMM ----------
__global__ __launch_bounds__(256, 3) void conv_gemm(const unsigned short* __restrict__ xhwc,
                                                    const unsigned short* __restrict__ ap,
                                                    const float* __restrict__ bias,
                                                    float* __restrict__ out) {
    // B tile: 3 input rows, per-w cell padded 64->72 halfwords (lane stride
    // 36 dwords -> 2-way bank aliasing only = free). Slack covers garbage
    // columns ow in [110,127] (+kw) staying in-bounds.
    __shared__ unsigned short ldsB[25600];        // 51.2 KB -> 3 blocks/CU
    const int oh = blockIdx.x;                    // 0..109
    const int n  = blockIdx.y;                    // 0..31
    const int t  = threadIdx.x;

    {   // stage B: 3 contiguous rows of xhwc = 2688 uint4
        const uint4v* src = (const uint4v*)(xhwc + ((size_t)(n * INH + oh) * INW) * 64);
        for (int c = t; c < 2688; c += 256) {
            int kh = c / 896;                      // 896 = 112w * 8 parts
            int r  = c - kh * 896;
            int w_ = r >> 3, part = r & 7;
            *(uint4v*)&ldsB[(kh * INW + w_) * 72 + part * 8] = src[c];
        }
    }
    __syncthreads();   // the ONLY barrier

    const int lane = t & 63;
    const int wave = t >> 6;
    const int m_base  = (wave >> 1) * 64;          // co half
    const int px_base = (wave & 1) * 64;           // px half
    const int l16  = lane & 15;
    const int quad = lane >> 4;                    // 0..3

    int pxw[4];
#pragma unroll
    for (int j = 0; j < 4; ++j) pxw[j] = px_base + j * 16 + l16;

    f32x4 acc[4][4] = {};                          // [m-tile][px-tile]
    const short8* A = (const short8*)ap;           // index kb*128 + m

    short8 abuf[2][4], bbuf[2][4];
    auto loadf = [&](int kc, short8* aa, short8* bb) {
        const int khw = kc >> 1;
        const int kh = khw / 3, kw = khw - kh * 3; // block-uniform
        const int ci0 = (kc & 1) * 32 + quad * 8;
#pragma unroll
        for (int i = 0; i < 4; ++i)
            aa[i] = A[(kc * 4 + quad) * COUT + (m_base + i * 16 + l16)];
#pragma unroll
        for (int j = 0; j < 4; ++j)
            bb[j] = *(const short8*)&ldsB[(kh * INW + pxw[j] + kw) * 72 + ci0];
    };

    loadf(0, abuf[0], bbuf[0]);
#pragma unroll
    for (int kc = 0; kc < 18; ++kc) {              // K chunks of 32, fully unrolled
        const int cur = kc & 1;
        if (kc < 17) loadf(kc + 1, abuf[cur ^ 1], bbuf[cur ^ 1]);  // prefetch
#pragma unroll
        for (int i = 0; i < 4; ++i)
#pragma unroll
            for (int j = 0; j < 4; ++j)
                acc[i][j] = __builtin_amdgcn_mfma_f32_16x16x32_bf16(
                    abuf[cur][i], bbuf[cur][j], acc[i][j], 0, 0, 0);
    }

    // C/D layout (m89-verified): col = lane&15 -> px(ow), row = quad*4+reg -> co
#pragma unroll
    for (int i = 0; i < 4; ++i) {
        const int co = m_base + i * 16 + quad * 4;
        const f32x4 bv = *(const f32x4*)&bias[co];
#pragma unroll
        for (int j = 0; j < 4; ++j) {
            const int ow = pxw[j];
            if (ow < OUTW) {
                const size_t ob = (((size_t)n * COUT + co) * OUTH + oh) * OUTW + ow;
#pragma unroll
                for (int r = 0; r < 4; ++r)
                    out[ob + (size_t)r * (OUTH * OUTW)] = acc[i][j][r] + bv[r];
            }
        }
    }
}

// ---------- fallback direct conv if ws too small ----------
#define TCO 16
__global__ __launch_bounds__(256) void conv_direct(const float* __restrict__ x,
                                                   const float* __restrict__ w,
                                                   const float* __restrict__ bias,
                                                   float* __restrict__ out) {
    int p = blockIdx.x * 256 + threadIdx.x;
    const int co0 = blockIdx.y * TCO;
    const bool valid = p < NPIX;
    if (!valid) p = 0;
    const int n = p / (OUTH * OUTW);
    const int rem = p - n * (OUTH * OUTW);
    const int oh = rem / OUTW;
    const int ow = rem - oh * OUTW;
    float acc[TCO];
#pragma unroll
    for (int t = 0; t < TCO; ++t) acc[t] = bias[co0 + t];
    const float* xb = x + ((size_t)n * CIN) * (INH * INW) + (size_t)oh * INW + ow;
    const float* wb = w + (size_t)co0 * CIN * 9;
    for (int ci = 0; ci < CIN; ++ci) {
        const float* xp = xb + (size_t)ci * (INH * INW);
        const float* wp = wb + ci * 9;
#pragma unroll
        for (int kh = 0; kh < 3; ++kh) {
            const float x0 = xp[kh * INW + 0];
            const float x1 = xp[kh * INW + 1];
            const float x2 = xp[kh * INW + 2];
#pragma unroll
            for (int t = 0; t < TCO; ++t) {
                const float* wt = wp + t * (CIN * 9) + kh * 3;
                acc[t] = fmaf(x0, wt[0], acc[t]);
                acc[t] = fmaf(x1, wt[1], acc[t]);
                acc[t] = fmaf(x2, wt[2], acc[t]);
            }
        }
    }
    if (valid) {
        const size_t ob = ((size_t)n * COUT + co0) * (OUTH * OUTW) + (size_t)oh * OUTW + ow;
#pragma unroll
        for (int t = 0; t < TCO; ++t)
            out[ob + (size_t)t * (OUTH * OUTW)] = acc[t];
    }
}

extern "C" void kernel_launch(void* const* d_in, const int* in_sizes, int n_in,
                              void* d_out, int out_size, void* d_ws, size_t ws_size,
                              hipStream_t stream) {
    const float* x    = (const float*)d_in[0];
    const float* w    = (const float*)d_in[1];
    const float* bias = (const float*)d_in[2];
    float* out        = (float*)d_out;

    const size_t xhwc_bytes = (size_t)NB * INH * INW * 64 * 2;   // 51,380,224
    const size_t ap_bytes   = (size_t)COUT * KTOT * 2;           // 147,456

    if (ws_size >= xhwc_bytes + ap_bytes) {
        unsigned short* xhwc = (unsigned short*)d_ws;
        unsigned short* apck = (unsigned short*)((char*)d_ws + xhwc_bytes);
        convert_x<<<dim3(INH, NB), 256, 0, stream>>>(x, xhwc);
        prepack_w<<<288, 256, 0, stream>>>(w, apck);
        conv_gemm<<<dim3(OUTH, NB), 256, 0, stream>>>(xhwc, apck, bias, out);
    } else {
        dim3 grid((NPIX + 255) / 256, COUT / TCO);
        conv_direct<<<grid, dim3(256), 0, stream>>>(x, w, bias, out);
    }
}